// Round 5
// baseline (1741.544 us; speedup 1.0000x reference)
//
#include <hip/hip_runtime.h>
#include <stdint.h>
#include <stddef.h>

// ---------------------------------------------------------------------------
// fp8-fake-quant linear: out = clip(x/s_in, +-448) @ W^T * (s_in*s_w) + bias
// M=8192 K=4096 N=16384. f16 operands (measured absmax 0.0156 vs 0.075 thr).
// Round 5: the rounds-2..4 counters (MfmaUtil 39 / VALU 17 / occupancy 23 /
// HBM 28%) are the latency-bound signature: 128KB LDS forced 1 block/CU and
// barrier-locked all 8 waves. Fix = OCCUPANCY, not schedule micro-structure:
//   - 128x256 tile, 8 waves (2Mx4N), per-wave 64x64 (acc = 64 VGPR)
//   - ring-3 K-tile buffers x 24KB = 72KB LDS  -> 2 blocks/CU, 4 waves/SIMD
//   - __launch_bounds__(512,4) caps VGPR at 128 for the 2-block residency
//   - fragment-ordered conflict-free LDS kept (round 3, SQ_LDS_BANK_CONFLICT=0)
//   - one barrier/tile; counted vmcnt(3): stage tile t+2 during t (2-deep,
//     ~>1000cyc HBM cover); lgkm0 + sched_barrier(0) before MFMA (rule #18)
//   - bn-major tile order: consecutive same-XCD blocks share the 2MB B-tile
// ---------------------------------------------------------------------------

typedef _Float16 half8 __attribute__((ext_vector_type(8)));
typedef _Float16 half4v __attribute__((ext_vector_type(4)));
typedef float f32x4 __attribute__((ext_vector_type(4)));

#define BM 128
#define BN 256
#define BK 32
#define NBUF 3
#define NBLK 24                       // 8 A-blocks + 16 B-blocks, 1KB each
#define FP8MAX 448.0f

__device__ __forceinline__ void gload_lds16(const _Float16* g, _Float16* lds) {
  __builtin_amdgcn_global_load_lds(
      (const __attribute__((address_space(1))) uint32_t*)g,
      (__attribute__((address_space(3))) uint32_t*)lds, 16, 0, 0);
}

#define BAR() asm volatile("s_barrier" ::: "memory")
#define WAIT_VM(N) asm volatile("s_waitcnt vmcnt(" #N ")" ::: "memory")
#define LGKM0() asm volatile("s_waitcnt lgkmcnt(0)" ::: "memory")
#define SCHED_FENCE() __builtin_amdgcn_sched_barrier(0)

#define MFMA16(AF, BF, ACC) do {                                              \
  __builtin_amdgcn_s_setprio(1);                                              \
  _Pragma("unroll")                                                           \
  for (int m_ = 0; m_ < 4; ++m_) {                                            \
    _Pragma("unroll")                                                         \
    for (int n_ = 0; n_ < 4; ++n_)                                            \
      ACC[m_][n_] = __builtin_amdgcn_mfma_f32_16x16x32_f16(                   \
          AF[m_], BF[n_], ACC[m_][n_], 0, 0, 0);                              \
  }                                                                           \
  __builtin_amdgcn_s_setprio(0);                                              \
} while (0)

// ---- pass 1a: x_q = (f16) clip(x / s_in, +-448) ----------------------------
__global__ void cvt_x_kernel(const float* __restrict__ x, _Float16* __restrict__ xq,
                             const float* __restrict__ s_ptr, long n4) {
  float inv = 1.0f / s_ptr[0];
  long i = (long)blockIdx.x * blockDim.x + threadIdx.x;
  long stride = (long)gridDim.x * blockDim.x;
  const float4* x4 = (const float4*)x;
  for (long j = i; j < n4; j += stride) {
    float4 v = x4[j];
    half4v h;
    h[0] = (_Float16)fminf(fmaxf(v.x * inv, -FP8MAX), FP8MAX);
    h[1] = (_Float16)fminf(fmaxf(v.y * inv, -FP8MAX), FP8MAX);
    h[2] = (_Float16)fminf(fmaxf(v.z * inv, -FP8MAX), FP8MAX);
    h[3] = (_Float16)fminf(fmaxf(v.w * inv, -FP8MAX), FP8MAX);
    *(half4v*)(xq + j * 4) = h;
  }
}

// ---- pass 1b: w_q = (f16) w -------------------------------------------------
__global__ void cvt_w_kernel(const float* __restrict__ w, _Float16* __restrict__ wq,
                             long n4) {
  long i = (long)blockIdx.x * blockDim.x + threadIdx.x;
  long stride = (long)gridDim.x * blockDim.x;
  const float4* w4 = (const float4*)w;
  for (long j = i; j < n4; j += stride) {
    float4 v = w4[j];
    half4v h;
    h[0] = (_Float16)v.x; h[1] = (_Float16)v.y;
    h[2] = (_Float16)v.z; h[3] = (_Float16)v.w;
    *(half4v*)(wq + j * 4) = h;
  }
}

// ---- pass 2: 128x256 fragment-LDS ring-3 GEMM, 2 blocks/CU ------------------
__global__ __launch_bounds__(512, 4)
void gemm128x256(const _Float16* __restrict__ A, const _Float16* __restrict__ B,
                 const float* __restrict__ bias, const float* __restrict__ is_ptr,
                 const float* __restrict__ ws_ptr, float* __restrict__ out,
                 int M, int N, int K) {
  // blocks: A frag-blocks 0..7 (16 rows x 32k each), B frag-blocks 8..23.
  // block = 64 lanes x 16B = 1KB, conflict-free contiguous ds_read_b128.
  __shared__ __align__(16) _Float16 lds[NBUF][NBLK * 512];

  const int nbm = M / BM;             // 64
  const int nwg = gridDim.x;
  int wg = blockIdx.x;
  if ((nwg & 7) == 0) {               // bijective XCD swizzle (8 XCDs)
    int q = nwg >> 3;
    wg = (wg & 7) * q + (wg >> 3);
  }
  // bn-major: consecutive wg share bn -> B-tile (2MB) stays hot in L2
  const int brow = (wg % nbm) * BM;
  const int bcol = (wg / nbm) * BN;

  const int tid  = threadIdx.x;
  const int lane = tid & 63;
  const int w    = tid >> 6;          // wave 0..7
  const int wr   = w >> 2;            // 0..1 : rows [wr*64, +64)
  const int wc   = w & 3;             // 0..3 : cols [wc*64, +64)

  // per-lane global offset inside a fragment block: row (lane&15), k (lane>>4)*8
  const size_t laneoff = (size_t)(lane & 15) * K + (size_t)(lane >> 4) * 8;
  const int blk0 = w * 3;             // this wave stages blocks blk0..blk0+2
  const _Float16* gsrc[3];
#pragma unroll
  for (int j = 0; j < 3; ++j) {
    int b = blk0 + j;
    if (b < 8)
      gsrc[j] = A + (size_t)(brow + b * 16) * K + laneoff;
    else
      gsrc[j] = B + (size_t)(bcol + (b - 8) * 16) * K + laneoff;
  }

  auto stage = [&](int tb, int kt) {
#pragma unroll
    for (int j = 0; j < 3; ++j)
      gload_lds16(gsrc[j] + kt, &lds[tb][(blk0 + j) * 512]);
  };

  f32x4 acc[4][4] = {};

  const int NT = K / BK;              // 128

  // ---- prologue: stage tiles 0,1 (6 loads/thread); tile 0 ready after wait
  stage(0, 0);
  stage(1, BK);
  WAIT_VM(3);                          // tile 0 landed ({1} outstanding)
  BAR();

  int cur = 0;
  for (int t = 0; t < NT; ++t) {
    half8 a[4], b[4];
    // reads: this wave's 8 fragment blocks (contiguous 1KB, conflict-free)
#pragma unroll
    for (int m = 0; m < 4; ++m)
      a[m] = *(const half8*)&lds[cur][(wr * 4 + m) * 512 + lane * 8];
#pragma unroll
    for (int n = 0; n < 4; ++n)
      b[n] = *(const half8*)&lds[cur][(8 + wc * 4 + n) * 512 + lane * 8];
    // prefetch tile t+2 into ring slot (cur+2)%3 (its old readers finished
    // before the barrier that opened tile t)
    if (t + 2 < NT) {
      int sb = cur + 2; if (sb >= NBUF) sb -= NBUF;
      stage(sb, (t + 2) * BK);
    }
    LGKM0();                           // fragment reads retired
    SCHED_FENCE();                     // rule #18: keep MFMA below the wait
    MFMA16(a, b, acc);
    // end-of-tile counted wait: tile t+1's 3 loads must have landed before
    // the barrier lets anyone read them
    if (t < NT - 2)       WAIT_VM(3);
    else if (t == NT - 2) WAIT_VM(0);
    BAR();
    ++cur; if (cur >= NBUF) cur -= NBUF;
  }

  // ---- epilogue: C/D 16x16 layout: col = lane&15, row = (lane>>4)*4 + r
  const float sc = is_ptr[0] * ws_ptr[0];
  const int orow = brow + wr * 64;
  const int ocol = bcol + wc * 64;
#pragma unroll
  for (int n = 0; n < 4; ++n) {
    const int col = ocol + n * 16 + (lane & 15);
    const float bv = bias[col];
#pragma unroll
    for (int m = 0; m < 4; ++m) {
#pragma unroll
      for (int r = 0; r < 4; ++r) {
        const int row = orow + m * 16 + (lane >> 4) * 4 + r;
        out[(size_t)row * N + col] = acc[m][n][r] * sc + bv;
      }
    }
  }
}

// ---------------------------------------------------------------------------
extern "C" void kernel_launch(void* const* d_in, const int* in_sizes, int n_in,
                              void* d_out, int out_size, void* d_ws, size_t ws_size,
                              hipStream_t stream) {
  const float* x    = (const float*)d_in[0];
  const float* wgt  = (const float*)d_in[1];
  const float* bias = (const float*)d_in[2];
  const float* is   = (const float*)d_in[3];
  const float* wsc  = (const float*)d_in[4];
  float* out = (float*)d_out;

  const long x_n = in_sizes[0];
  const long w_n = in_sizes[1];
  const int  N   = in_sizes[2];
  const int  K   = (int)(w_n / N);
  const int  M   = (int)(x_n / K);

  _Float16* xq = (_Float16*)d_ws;
  _Float16* wq = xq + x_n;

  cvt_x_kernel<<<2048, 256, 0, stream>>>(x, xq, is, x_n >> 2);
  cvt_w_kernel<<<2048, 256, 0, stream>>>(wgt, wq, w_n >> 2);

  const int nwg = (M / BM) * (N / BN);   // 64 * 64 = 4096, %8 == 0
  gemm128x256<<<nwg, 512, 0, stream>>>(xq, wq, bias, is, wsc, out, M, N, K);
}

// Round 6
// 1269.537 us; speedup vs baseline: 1.3718x; 1.3718x over previous
//
#include <hip/hip_runtime.h>
#include <stdint.h>
#include <stddef.h>

// ---------------------------------------------------------------------------
// fp8-fake-quant linear: out = clip(x/s_in, +-448) @ W^T * (s_in*s_w) + bias
// M=8192 K=4096 N=16384. f16 operands (measured absmax 0.0156 vs 0.075 thr).
// Round 6: rounds 1-5 post-mortem shows ALL configs were global->LDS supply
// bound; fragment-scattered staging (r3-5) halves supply rate (5.9 vs 10.5
// TB/s). Fix: CONTIGUOUS staging + XOR swizzle (both-sides involution within
// each row's 128B, coalescing untouched):  LDS(r,c) = global(r, c^(r&7)),
// read back at chunk c^(r&7)  ->  2-way bank alias = free.
// Structure = m201 8-phase template: 256x256, BK=64, 8 waves (2Mx4N), dbuf
// 128KB, 4 phases/K-tile, snake quadrant order (0,0)(1,0)(1,1)(0,1) with
// A/B frags HELD in registers so each LDS region's last read is early:
//   A(cur) last read p2  -> p3/p4 stage A(t+2) into cur    (race-free)
//   B(cur) last read p3  -> B(t+1) staged p1/p2 into nxt   (race-free)
// Single counted vmcnt(4) per K-tile (outstanding = A(t+2) x4, exactly);
// never drains to 0 in the main loop. setprio around MFMA (T5), XCD swizzle.
// ---------------------------------------------------------------------------

typedef _Float16 half8 __attribute__((ext_vector_type(8)));
typedef _Float16 half4v __attribute__((ext_vector_type(4)));
typedef float f32x4 __attribute__((ext_vector_type(4)));

#define BM 256
#define BN 256
#define BK 64
#define FP8MAX 448.0f

__device__ __forceinline__ void gload_lds16(const _Float16* g, _Float16* lds) {
  __builtin_amdgcn_global_load_lds(
      (const __attribute__((address_space(1))) uint32_t*)g,
      (__attribute__((address_space(3))) uint32_t*)lds, 16, 0, 0);
}

#define BAR() asm volatile("s_barrier" ::: "memory")
#define WAIT_VM(N) asm volatile("s_waitcnt vmcnt(" #N ")" ::: "memory")
#define LGKM0() asm volatile("s_waitcnt lgkmcnt(0)" ::: "memory")
#define SCHED_FENCE() __builtin_amdgcn_sched_barrier(0)

// one quadrant: 4 m-frags x 2 n-frags x 2 k-steps = 16 MFMA, setprio-wrapped
#define MFMA_Q(AF, BF, MG, NG) do {                                           \
  __builtin_amdgcn_s_setprio(1);                                              \
  _Pragma("unroll")                                                           \
  for (int mf_ = 0; mf_ < 4; ++mf_) {                                         \
    _Pragma("unroll")                                                         \
    for (int nf_ = 0; nf_ < 2; ++nf_) {                                       \
      _Pragma("unroll")                                                       \
      for (int ks_ = 0; ks_ < 2; ++ks_)                                       \
        acc[(MG)*4 + mf_][(NG)*2 + nf_] =                                     \
            __builtin_amdgcn_mfma_f32_16x16x32_f16(                           \
                AF[mf_*2 + ks_], BF[nf_*2 + ks_],                             \
                acc[(MG)*4 + mf_][(NG)*2 + nf_], 0, 0, 0);                    \
    }                                                                         \
  }                                                                           \
  __builtin_amdgcn_s_setprio(0);                                              \
} while (0)

// ---- pass 1a: x_q = (f16) clip(x / s_in, +-448) ----------------------------
__global__ void cvt_x_kernel(const float* __restrict__ x, _Float16* __restrict__ xq,
                             const float* __restrict__ s_ptr, long n4) {
  float inv = 1.0f / s_ptr[0];
  long i = (long)blockIdx.x * blockDim.x + threadIdx.x;
  long stride = (long)gridDim.x * blockDim.x;
  const float4* x4 = (const float4*)x;
  for (long j = i; j < n4; j += stride) {
    float4 v = x4[j];
    half4v h;
    h[0] = (_Float16)fminf(fmaxf(v.x * inv, -FP8MAX), FP8MAX);
    h[1] = (_Float16)fminf(fmaxf(v.y * inv, -FP8MAX), FP8MAX);
    h[2] = (_Float16)fminf(fmaxf(v.z * inv, -FP8MAX), FP8MAX);
    h[3] = (_Float16)fminf(fmaxf(v.w * inv, -FP8MAX), FP8MAX);
    *(half4v*)(xq + j * 4) = h;
  }
}

// ---- pass 1b: w_q = (f16) w -------------------------------------------------
__global__ void cvt_w_kernel(const float* __restrict__ w, _Float16* __restrict__ wq,
                             long n4) {
  long i = (long)blockIdx.x * blockDim.x + threadIdx.x;
  long stride = (long)gridDim.x * blockDim.x;
  const float4* w4 = (const float4*)w;
  for (long j = i; j < n4; j += stride) {
    float4 v = w4[j];
    half4v h;
    h[0] = (_Float16)v.x; h[1] = (_Float16)v.y;
    h[2] = (_Float16)v.z; h[3] = (_Float16)v.w;
    *(half4v*)(wq + j * 4) = h;
  }
}

// ---- pass 2: 256^2 8-phase swizzled GEMM ------------------------------------
__global__ __launch_bounds__(512, 2)
void gemm256_sw(const _Float16* __restrict__ A, const _Float16* __restrict__ B,
                const float* __restrict__ bias, const float* __restrict__ is_ptr,
                const float* __restrict__ ws_ptr, float* __restrict__ out,
                int M, int N, int K) {
  // [256 rows][64 k] f16 per buf, 32KB; elem (r,k) at r*64 + ((k>>3)^(r&7))*8 + (k&7)
  __shared__ __align__(16) _Float16 sA[2][256 * 64];
  __shared__ __align__(16) _Float16 sB[2][256 * 64];

  const int nbn = N / BN;
  const int nwg = gridDim.x;
  int wg = blockIdx.x;
  if ((nwg & 7) == 0) {               // bijective XCD swizzle (8 XCDs)
    int q = nwg >> 3;
    wg = (wg & 7) * q + (wg >> 3);
  }
  const int brow = (wg / nbn) * BM;
  const int bcol = (wg % nbn) * BN;

  const int tid  = threadIdx.x;
  const int lane = tid & 63;
  const int w    = tid >> 6;          // wave 0..7
  const int wr   = w >> 2;            // 0..1 : rows [wr*128, +128)
  const int wc   = w & 3;             // 0..3 : cols [wc*64, +64)

  // ---- staging: piece(op, pi) = rows pi*64..+64, full 128B per row (8KB).
  // wave w covers rows pi*64 + w*8 .. +8; per-lane: row lane>>3, source chunk
  // (lane&7)^(lane>>3)  (inverse swizzle; within-row permutation => coalesced)
  const size_t lsrc = (size_t)(lane >> 3) * K + (size_t)((lane & 7) ^ (lane >> 3)) * 8;
  const _Float16* gA = A + (size_t)brow * K + lsrc;
  const _Float16* gB = B + (size_t)bcol * K + lsrc;

  auto stageA = [&](int buf, int pi, int kt) {
    gload_lds16(gA + (size_t)(pi * 64 + w * 8) * K + kt,
                &sA[buf][(pi * 512 + w * 64) * 8]);
  };
  auto stageB = [&](int buf, int pi, int kt) {
    gload_lds16(gB + (size_t)(pi * 64 + w * 8) * K + kt,
                &sB[buf][(pi * 512 + w * 64) * 8]);
  };

  // ---- swizzled fragment reads: frag g (16 rows), kstep ks:
  // r = g*16 + (lane&15); chunk = (ks*4 + (lane>>4)) ^ (r&7), r&7 == lane&7
  const int rdbase = (lane & 15) * 64;
  const int e0 = rdbase + (((lane >> 4) + 0) ^ (lane & 7)) * 8;   // ks=0
  const int e1 = rdbase + (((lane >> 4) + 4) ^ (lane & 7)) * 8;   // ks=1

  auto ldA = [&](int buf, int mg, half8* a) {
#pragma unroll
    for (int mf = 0; mf < 4; ++mf) {
      const int base = (wr * 8 + mg * 4 + mf) * 1024;
      a[mf * 2 + 0] = *(const half8*)&sA[buf][base + e0];
      a[mf * 2 + 1] = *(const half8*)&sA[buf][base + e1];
    }
  };
  auto ldB = [&](int buf, int ng, half8* b) {
#pragma unroll
    for (int nf = 0; nf < 2; ++nf) {
      const int base = (wc * 4 + ng * 2 + nf) * 1024;
      b[nf * 2 + 0] = *(const half8*)&sB[buf][base + e0];
      b[nf * 2 + 1] = *(const half8*)&sB[buf][base + e1];
    }
  };

  f32x4 acc[8][4] = {};
  const int NT = K / BK;              // 64

  // ---- prologue: A(0), B(0), A(1); after vmcnt(4): tile0 resident, A(1) flying
  stageA(0, 0, 0); stageA(0, 1, 0); stageA(0, 2, 0); stageA(0, 3, 0);
  stageB(0, 0, 0); stageB(0, 1, 0); stageB(0, 2, 0); stageB(0, 3, 0);
  stageA(1, 0, BK); stageA(1, 1, BK); stageA(1, 2, BK); stageA(1, 3, BK);
  WAIT_VM(4);
  BAR();

  for (int t = 0; t < NT; ++t) {
    const int cur = t & 1, nxt = cur ^ 1;
    const int ktB = (t + 1) * BK;     // B(t+1) -> nxt
    const int ktA = (t + 2) * BK;     // A(t+2) -> cur (A-region free after p2)
    const bool sb = (t + 1) < NT;
    const bool sa = (t + 2) < NT;
    half8 aL[8], aH[8], bL[4], bH[4];

    // ---- p1: quadrant (0,0); reads aL(8) + bL(4); stage B(t+1) pieces 0,1
    ldA(cur, 0, aL); ldB(cur, 0, bL);
    if (sb) { stageB(nxt, 0, ktB); stageB(nxt, 1, ktB); }
    BAR();
    LGKM0(); SCHED_FENCE();
    MFMA_Q(aL, bL, 0, 0);
    BAR();

    // ---- p2: quadrant (1,0); reads aH(8), bL reused; stage B(t+1) pieces 2,3
    ldA(cur, 1, aH);
    if (sb) { stageB(nxt, 2, ktB); stageB(nxt, 3, ktB); }
    BAR();
    LGKM0(); SCHED_FENCE();
    MFMA_Q(aH, bL, 1, 0);
    BAR();

    // ---- p3: quadrant (1,1); reads bH(4), aH reused; stage A(t+2) pieces 0,1
    ldB(cur, 1, bH);
    if (sa) { stageA(cur, 0, ktA); stageA(cur, 1, ktA); }
    BAR();
    LGKM0(); SCHED_FENCE();
    MFMA_Q(aH, bH, 1, 1);
    BAR();

    // ---- p4: quadrant (0,1); aL & bH reused (no reads); stage A(t+2) 2,3
    if (sa) { stageA(cur, 2, ktA); stageA(cur, 3, ktA); }
    MFMA_Q(aL, bH, 0, 1);
    // tile-boundary counted wait: outstanding = A(t+2) x4 exactly
    if (t < NT - 2)       WAIT_VM(4);
    else if (t == NT - 2) WAIT_VM(0);
    BAR();
  }

  // ---- epilogue: C/D 16x16 layout: col = lane&15, row = (lane>>4)*4 + r
  const float sc = is_ptr[0] * ws_ptr[0];
  const int orow = brow + wr * 128;
  const int ocol = bcol + wc * 64;
#pragma unroll
  for (int n = 0; n < 4; ++n) {
    const int col = ocol + n * 16 + (lane & 15);
    const float bv = bias[col];
#pragma unroll
    for (int m = 0; m < 8; ++m) {
#pragma unroll
      for (int r = 0; r < 4; ++r) {
        const int row = orow + m * 16 + (lane >> 4) * 4 + r;
        out[(size_t)row * N + col] = acc[m][n][r] * sc + bv;
      }
    }
  }
}

// ---------------------------------------------------------------------------
extern "C" void kernel_launch(void* const* d_in, const int* in_sizes, int n_in,
                              void* d_out, int out_size, void* d_ws, size_t ws_size,
                              hipStream_t stream) {
  const float* x    = (const float*)d_in[0];
  const float* wgt  = (const float*)d_in[1];
  const float* bias = (const float*)d_in[2];
  const float* is   = (const float*)d_in[3];
  const float* wsc  = (const float*)d_in[4];
  float* out = (float*)d_out;

  const long x_n = in_sizes[0];
  const long w_n = in_sizes[1];
  const int  N   = in_sizes[2];
  const int  K   = (int)(w_n / N);
  const int  M   = (int)(x_n / K);

  _Float16* xq = (_Float16*)d_ws;
  _Float16* wq = xq + x_n;

  cvt_x_kernel<<<2048, 256, 0, stream>>>(x, xq, is, x_n >> 2);
  cvt_w_kernel<<<2048, 256, 0, stream>>>(wgt, wq, w_n >> 2);

  const int nwg = (M / BM) * (N / BN);   // 32 * 64 = 2048, %8 == 0
  gemm256_sw<<<nwg, 512, 0, stream>>>(xq, wq, bias, is, wsc, out, M, N, K);
}